// Round 8
// baseline (347.643 us; speedup 1.0000x reference)
//
#include <hip/hip_runtime.h>
#include <hip/hip_bf16.h>
#include <stdint.h>

typedef unsigned short u16;
typedef _Float16 f16;
typedef __attribute__((ext_vector_type(4))) float f32x4;
typedef __attribute__((ext_vector_type(8))) _Float16 h16x8;
typedef __attribute__((ext_vector_type(4))) _Float16 h16x4;
typedef __attribute__((ext_vector_type(2))) _Float16 h16x2;

#define LN_EPS 1e-5f
#define ATT_EPS 1e-8f

// ---------------- init slots: mu + exp(logsigma)*noise ----------------
__global__ __launch_bounds__(256) void init_slots_k(
    const float* __restrict__ noise, const float* __restrict__ mu,
    const float* __restrict__ lsig, float* __restrict__ slots)
{
  int i = blockIdx.x * 256 + threadIdx.x;   // 65536 total
  int d = i & 255;
  slots[i] = mu[d] + __expf(lsig[d]) * noise[i];
}

// ---------------- prep weights ----------------
// f16 d-paired packs for all combine matvecs + WkT16 (slot_t).
__global__ __launch_bounds__(256) void prep_w_k(
    const float* __restrict__ Wk, const float* __restrict__ Wv,
    const float* __restrict__ Wc, const float* __restrict__ wih,
    const float* __restrict__ whh, const float* __restrict__ W1,
    const float* __restrict__ W2, const float* __restrict__ Wq,
    f16* __restrict__ WkT16, h16x2* __restrict__ WkT_p,
    h16x2* __restrict__ Wv_p, h16x2* __restrict__ Wc_p,
    h16x2* __restrict__ wih_p, h16x2* __restrict__ whh_p,
    h16x2* __restrict__ W1_p, h16x2* __restrict__ W2_p,
    h16x2* __restrict__ Wq_p)
{
  int i = blockIdx.x * 256 + threadIdx.x;   // 0..65535
  int col = i & 255, dp = i >> 8;
  // WkT16[c][kd] = Wk[kd][c]  (c=dp, kd=col)
  WkT16[i] = (f16)Wk[col * 256 + dp];
  // W2_p (512x256 -> 256 pairs x 256)
  {
    h16x2 v; v[0] = (f16)W2[(2 * dp) * 256 + col]; v[1] = (f16)W2[(2 * dp + 1) * 256 + col];
    W2_p[i] = v;
  }
  // W1_p (256x512 -> 128 pairs x 512)
  {
    int c5 = i & 511, dp1 = i >> 9;
    h16x2 v; v[0] = (f16)W1[(2 * dp1) * 512 + c5]; v[1] = (f16)W1[(2 * dp1 + 1) * 512 + c5];
    W1_p[i] = v;
  }
  if (dp < 128) {
    h16x2 v;
    v[0] = (f16)Wv[(2 * dp) * 256 + col]; v[1] = (f16)Wv[(2 * dp + 1) * 256 + col];
    Wv_p[i] = v;
    v[0] = (f16)Wc[(2 * dp) * 256 + col]; v[1] = (f16)Wc[(2 * dp + 1) * 256 + col];
    Wc_p[i] = v;
    v[0] = (f16)Wq[(2 * dp) * 256 + col]; v[1] = (f16)Wq[(2 * dp + 1) * 256 + col];
    Wq_p[i] = v;
    // WkT_p[(h*32+dpp)][d2] = pair of Wk[d2][h*64+2dpp ..+1]
    int h = dp >> 5, dpp = dp & 31;
    v[0] = (f16)Wk[col * 256 + h * 64 + 2 * dpp];
    v[1] = (f16)Wk[col * 256 + h * 64 + 2 * dpp + 1];
    WkT_p[i] = v;
#pragma unroll
    for (int g = 0; g < 3; g++) {
      h16x2 a, b;
      a[0] = (f16)wih[(g * 256 + col) * 256 + 2 * dp];
      a[1] = (f16)wih[(g * 256 + col) * 256 + 2 * dp + 1];
      b[0] = (f16)whh[(g * 256 + col) * 256 + 2 * dp];
      b[1] = (f16)whh[(g * 256 + col) * 256 + 2 * dp + 1];
      wih_p[dp * 768 + g * 256 + col] = a;
      whh_p[dp * 768 + g * 256 + col] = b;
    }
  }
}

// ---------------- pure LN pass: xln16 = LN(inputs) as f16 ----------------
// grid 2048, block 256 (4 waves): one wave per row, 16 rows/wave
__global__ __launch_bounds__(256) void ln_x_k(
    const float* __restrict__ inputs, const float* __restrict__ g_in,
    const float* __restrict__ b_in, f16* __restrict__ xln16)
{
  int t = threadIdx.x, w = t >> 6, l = t & 63;
  float4 gv = *(const float4*)(g_in + l * 4);
  float4 bv = *(const float4*)(b_in + l * 4);
  long row0 = (long)blockIdx.x * 64 + w * 16;
#pragma unroll 2
  for (int i = 0; i < 16; i++) {
    long r = row0 + i;
    float4 x = *(const float4*)(inputs + r * 256 + l * 4);
    float s1 = x.x + x.y + x.z + x.w;
    float s2 = x.x * x.x + x.y * x.y + x.z * x.z + x.w * x.w;
#pragma unroll
    for (int off = 1; off < 64; off <<= 1) {
      s1 += __shfl_xor(s1, off);
      s2 += __shfl_xor(s2, off);
    }
    float m = s1 * (1.f / 256.f);
    float var = s2 * (1.f / 256.f) - m * m;
    float rs = rsqrtf(var + LN_EPS);
    h16x4 o;
    o[0] = (f16)((x.x - m) * rs * gv.x + bv.x);
    o[1] = (f16)((x.y - m) * rs * gv.y + bv.y);
    o[2] = (f16)((x.z - m) * rs * gv.z + bv.z);
    o[3] = (f16)((x.w - m) * rs * gv.w + bv.w);
    *(h16x4*)(xln16 + r * 256 + l * 4) = o;
  }
}

// ---------------- t = (LN(slots)@Wq) projected through Wk heads, x SCALE ----
// grid 256 (one slot row per block), block 1024 (iter-0 only)
__global__ __launch_bounds__(1024) void slot_t_k(
    const float* __restrict__ slots, const float* __restrict__ g_sl,
    const float* __restrict__ b_sl, const float* __restrict__ Wq,
    const f16* __restrict__ WkT16, f16* __restrict__ tq)
{
  __shared__ float ln[256];
  __shared__ float qs[256];
  __shared__ float part[4][256];
  __shared__ float red[8];
  int t = threadIdx.x;
  int i = blockIdx.x;
  if (t < 256) {
    float x = slots[i * 256 + t];
    float a = x, bq = x * x;
#pragma unroll
    for (int off = 32; off; off >>= 1) { a += __shfl_down(a, off); bq += __shfl_down(bq, off); }
    if ((t & 63) == 0) { red[t >> 6] = a; red[4 + (t >> 6)] = bq; }
  }
  __syncthreads();
  if (t < 256) {
    float x = slots[i * 256 + t];
    float S1 = red[0] + red[1] + red[2] + red[3];
    float S2 = red[4] + red[5] + red[6] + red[7];
    float m = S1 * (1.f / 256.f);
    float var = S2 * (1.f / 256.f) - m * m;
    float rstd = rsqrtf(var + LN_EPS);
    ln[t] = (x - m) * rstd * g_sl[t] + b_sl[t];
  }
  __syncthreads();
  int col = t & 255, ks = t >> 8;
  float acc = 0.f;
#pragma unroll 16
  for (int dd = 0; dd < 64; dd++) {
    int d = ks * 64 + dd;
    acc += ln[d] * Wq[d * 256 + col];
  }
  part[ks][col] = acc;
  __syncthreads();
  if (t < 256) qs[t] = part[0][t] + part[1][t] + part[2][t] + part[3][t];
  __syncthreads();
  int h = t >> 8, d2 = t & 255;
  float tt = 0.f;
#pragma unroll 8
  for (int dp = 0; dp < 64; dp++)
    tt += qs[h * 64 + dp] * (float)WkT16[(h * 64 + dp) * 256 + d2];
  tq[((i >> 3) * 32 + h * 8 + (i & 7)) * 256 + d2] = (f16)(tt * 0.125f);
}

// ---------------- fused attn: MFMA dots + shuffle softmax + MFMA PV ----------
// grid (32 b, 32 nchunk of 128 n), block 256 (4 waves). 2 subtiles of 64 n.
__global__ __launch_bounds__(256, 3) void attn_fused_k(
    const f16* __restrict__ xln16, const f16* __restrict__ tq,
    f16* __restrict__ y_part, float* __restrict__ sums_part)
{
  __shared__ u16 xsT[256 * 64];      // 32KB: addr = d*128 + ((n8 ^ (d&7))<<4)
  __shared__ u16 attT[32 * 64];      // 4KB:  addr = hs*128 + ((n8 ^ (hs&7))<<4)
  __shared__ float asum_s[4][32];
  int b = blockIdx.x, nc = blockIdx.y, t = threadIdx.x;
  int nb = nc * 128;
  int w = t >> 6, l = t & 63;
  int lc = l & 15, lg = l >> 4;
  h16x8 tb0[8], tb1[8];
#pragma unroll
  for (int k0 = 0; k0 < 8; k0++) {
    tb0[k0] = *(const h16x8*)(tq + (b * 32 + lc) * 256 + k0 * 32 + lg * 8);
    tb1[k0] = *(const h16x8*)(tq + (b * 32 + lc + 16) * 256 + k0 * 32 + lg * 8);
  }
  f32x4 acc0[4], acc1[4];
#pragma unroll
  for (int dt = 0; dt < 4; dt++) { acc0[dt] = (f32x4){0,0,0,0}; acc1[dt] = (f32x4){0,0,0,0}; }
  float as0 = 0.f, as1 = 0.f;

  for (int sub = 0; sub < 2; sub++) {
    __syncthreads();
    {
      int nl8 = t >> 5, dchunk = t & 31;
      const f16* gp = xln16 + ((long)(b * 4096 + nb + sub * 64 + nl8 * 8)) * 256 + dchunk * 8;
      h16x8 v0 = *(const h16x8*)(gp);
      h16x8 v1 = *(const h16x8*)(gp + 256);
      h16x8 v2 = *(const h16x8*)(gp + 512);
      h16x8 v3 = *(const h16x8*)(gp + 768);
      h16x8 v4 = *(const h16x8*)(gp + 1024);
      h16x8 v5 = *(const h16x8*)(gp + 1280);
      h16x8 v6 = *(const h16x8*)(gp + 1536);
      h16x8 v7 = *(const h16x8*)(gp + 1792);
#pragma unroll
      for (int j = 0; j < 8; j++) {
        h16x8 o;
        o[0] = v0[j]; o[1] = v1[j]; o[2] = v2[j]; o[3] = v3[j];
        o[4] = v4[j]; o[5] = v5[j]; o[6] = v6[j]; o[7] = v7[j];
        int d = dchunk * 8 + j;
        *(h16x8*)((char*)xsT + d * 128 + ((nl8 ^ j) << 4)) = o;
      }
    }
    f32x4 D0 = {0,0,0,0}, D1 = {0,0,0,0};
    {
      const f16* ga = xln16 + ((long)(b * 4096 + nb + sub * 64 + w * 16 + lc)) * 256 + lg * 8;
#pragma unroll
      for (int k0 = 0; k0 < 8; k0++) {
        h16x8 af = *(const h16x8*)(ga + k0 * 32);
        D0 = __builtin_amdgcn_mfma_f32_16x16x32_f16(af, tb0[k0], D0, 0, 0, 0);
        D1 = __builtin_amdgcn_mfma_f32_16x16x32_f16(af, tb1[k0], D1, 0, 0, 0);
      }
    }
    h16x4 pk0, pk1;
#pragma unroll
    for (int r = 0; r < 4; r++) {
      float d0 = D0[r], d1 = D1[r];
      float m0 = d0, m1 = d1;
      m0 = fmaxf(m0, __shfl_xor(m0, 1)); m0 = fmaxf(m0, __shfl_xor(m0, 2)); m0 = fmaxf(m0, __shfl_xor(m0, 4));
      m1 = fmaxf(m1, __shfl_xor(m1, 1)); m1 = fmaxf(m1, __shfl_xor(m1, 2)); m1 = fmaxf(m1, __shfl_xor(m1, 4));
      float e0 = __expf(d0 - m0), e1 = __expf(d1 - m1);
      float s0 = e0, s1 = e1;
      s0 += __shfl_xor(s0, 1); s0 += __shfl_xor(s0, 2); s0 += __shfl_xor(s0, 4);
      s1 += __shfl_xor(s1, 1); s1 += __shfl_xor(s1, 2); s1 += __shfl_xor(s1, 4);
      f16 a0h = (f16)(e0 / s0), a1h = (f16)(e1 / s1);
      as0 += (float)a0h; as1 += (float)a1h;
      pk0[r] = a0h; pk1[r] = a1h;
    }
    {
      int slot = w * 2 + (lg >> 1);
      int boff = (lg & 1) * 8;
      *(h16x4*)((char*)attT + lc * 128 + ((slot ^ (lc & 7)) << 4) + boff) = pk0;
      *(h16x4*)((char*)attT + (lc + 16) * 128 + ((slot ^ (lc & 7)) << 4) + boff) = pk1;
    }
    __syncthreads();
    h16x8 A00, A01, A10, A11;
    {
      int hs0 = lc, hs1 = 16 + lc, sw = lc & 7;
      A00 = *(const h16x8*)((char*)attT + hs0 * 128 + ((lg ^ sw) << 4));
      A01 = *(const h16x8*)((char*)attT + hs0 * 128 + (((4 + lg) ^ sw) << 4));
      A10 = *(const h16x8*)((char*)attT + hs1 * 128 + ((lg ^ sw) << 4));
      A11 = *(const h16x8*)((char*)attT + hs1 * 128 + (((4 + lg) ^ sw) << 4));
    }
#pragma unroll
    for (int dt = 0; dt < 4; dt++) {
      int d = w * 64 + dt * 16 + lc;
      h16x8 B0 = *(const h16x8*)((char*)xsT + d * 128 + ((lg ^ (d & 7)) << 4));
      h16x8 B1 = *(const h16x8*)((char*)xsT + d * 128 + (((4 + lg) ^ (d & 7)) << 4));
      acc0[dt] = __builtin_amdgcn_mfma_f32_16x16x32_f16(A00, B0, acc0[dt], 0, 0, 0);
      acc0[dt] = __builtin_amdgcn_mfma_f32_16x16x32_f16(A01, B1, acc0[dt], 0, 0, 0);
      acc1[dt] = __builtin_amdgcn_mfma_f32_16x16x32_f16(A10, B0, acc1[dt], 0, 0, 0);
      acc1[dt] = __builtin_amdgcn_mfma_f32_16x16x32_f16(A11, B1, acc1[dt], 0, 0, 0);
    }
  }
  as0 += __shfl_xor(as0, 16); as0 += __shfl_xor(as0, 32);
  as1 += __shfl_xor(as1, 16); as1 += __shfl_xor(as1, 32);
  if (l < 16) { asum_s[w][l] = as0; asum_s[w][l + 16] = as1; }
  __syncthreads();
  if (t < 32)
    sums_part[(nc * 32 + b) * 32 + t] =
        asum_s[0][t] + asum_s[1][t] + asum_s[2][t] + asum_s[3][t];
  long ybase = ((long)(nc * 32 + b) * 32) * 256;
#pragma unroll
  for (int reg = 0; reg < 4; reg++) {
    int hsA = lg * 4 + reg;
#pragma unroll
    for (int dt = 0; dt < 4; dt++) {
      int d = w * 64 + dt * 16 + lc;
      y_part[ybase + hsA * 256 + d] = (f16)acc0[dt][reg];
      y_part[ybase + (16 + hsA) * 256 + d] = (f16)acc1[dt][reg];
    }
  }
}

// ---------------- combine: y-reduce + Wv + Wc + GRU(1-pass) + LN + MLP (+ next-t) --
// grid 256 (one slot row per block), block 1024. f16-pair weights.
__global__ __launch_bounds__(1024) void combine_k(
    const f16* __restrict__ y_part, const float* __restrict__ sums_part,
    float* __restrict__ slots,
    const h16x2* __restrict__ Wv_p, const h16x2* __restrict__ Wc_p,
    const h16x2* __restrict__ wih_p, const h16x2* __restrict__ whh_p,
    const float* __restrict__ bih, const float* __restrict__ bhh,
    const float* __restrict__ g_ml, const float* __restrict__ b_ml,
    const h16x2* __restrict__ W1_p, const float* __restrict__ b1,
    const h16x2* __restrict__ W2_p, const float* __restrict__ b2,
    const float* __restrict__ g_sl, const float* __restrict__ b_sl,
    const h16x2* __restrict__ Wq_p, const h16x2* __restrict__ WkT_p,
    f16* __restrict__ tq, int cq)
{
  __shared__ float ysn[4][256];
  __shared__ float uls[256], cls[256], hls[256], sns[256], lns[256];
  __shared__ float gia[3][256], gha[3][256];
  __shared__ float hid[512];
  __shared__ float part2[4][256];
  __shared__ float part6[4][256][7];   // 7: pad to kill bank conflicts
  __shared__ float part5[2][512];
  __shared__ float red[8];
  int t = threadIdx.x;
  int i = blockIdx.x;
  int b = i >> 3, k = i & 7;
  // ---- y-reduce + normalize
  {
    int j = t >> 8, d = t & 255;
    float den = ATT_EPS, yv = 0.f;
#pragma unroll 8
    for (int ncq = 0; ncq < 32; ncq++) {
      int hsrow = (ncq * 32 + b) * 32 + j * 8 + k;
      den += sums_part[hsrow];
      yv += (float)y_part[(long)hsrow * 256 + d];
    }
    ysn[j][d] = yv / den;
    if (t < 256) hls[t] = slots[i * 256 + t];
  }
  __syncthreads();
  int col = t & 255, ks = t >> 8;
  int hcol = col >> 6;
  // ---- Wv
  {
    float acc = 0.f;
#pragma unroll 16
    for (int dd = 0; dd < 32; dd++) {
      int dp = ks * 32 + dd;
      h16x2 wv = Wv_p[dp * 256 + col];
      acc += ysn[hcol][2 * dp] * (float)wv[0] + ysn[hcol][2 * dp + 1] * (float)wv[1];
    }
    part2[ks][col] = acc;
  }
  __syncthreads();
  if (t < 256) uls[t] = part2[0][t] + part2[1][t] + part2[2][t] + part2[3][t];
  __syncthreads();
  // ---- Wc
  {
    float acc = 0.f;
#pragma unroll 16
    for (int dd = 0; dd < 32; dd++) {
      int dp = ks * 32 + dd;
      h16x2 wv = Wc_p[dp * 256 + col];
      acc += uls[2 * dp] * (float)wv[0] + uls[2 * dp + 1] * (float)wv[1];
    }
    part2[ks][col] = acc;
  }
  __syncthreads();
  if (t < 256) cls[t] = part2[0][t] + part2[1][t] + part2[2][t] + part2[3][t];
  __syncthreads();
  // ---- GRU: all 6 gate dot-products in one d-pass
  {
    float a0 = 0.f, a1 = 0.f, a2 = 0.f, h0a = 0.f, h1a = 0.f, h2a = 0.f;
#pragma unroll 8
    for (int dd = 0; dd < 32; dd++) {
      int dp = ks * 32 + dd;
      float c0 = cls[2 * dp], c1 = cls[2 * dp + 1];
      float hh0 = hls[2 * dp], hh1 = hls[2 * dp + 1];
      h16x2 wi0 = wih_p[dp * 768 + col];
      h16x2 wi1 = wih_p[dp * 768 + 256 + col];
      h16x2 wi2 = wih_p[dp * 768 + 512 + col];
      h16x2 wh0 = whh_p[dp * 768 + col];
      h16x2 wh1 = whh_p[dp * 768 + 256 + col];
      h16x2 wh2 = whh_p[dp * 768 + 512 + col];
      a0 += c0 * (float)wi0[0] + c1 * (float)wi0[1];
      a1 += c0 * (float)wi1[0] + c1 * (float)wi1[1];
      a2 += c0 * (float)wi2[0] + c1 * (float)wi2[1];
      h0a += hh0 * (float)wh0[0] + hh1 * (float)wh0[1];
      h1a += hh0 * (float)wh1[0] + hh1 * (float)wh1[1];
      h2a += hh0 * (float)wh2[0] + hh1 * (float)wh2[1];
    }
    part6[ks][col][0] = a0; part6[ks][col][1] = a1; part6[ks][col][2] = a2;
    part6[ks][col][3] = h0a; part6[ks][col][4] = h1a; part6[ks][col][5] = h2a;
  }
  __syncthreads();
  if (t < 256) {
    gia[0][t] = part6[0][t][0] + part6[1][t][0] + part6[2][t][0] + part6[3][t][0] + bih[t];
    gia[1][t] = part6[0][t][1] + part6[1][t][1] + part6[2][t][1] + part6[3][t][1] + bih[256 + t];
    gia[2][t] = part6[0][t][2] + part6[1][t][2] + part6[2][t][2] + part6[3][t][2] + bih[512 + t];
  } else if (t < 512) {
    int c = t & 255;
    gha[0][c] = part6[0][c][3] + part6[1][c][3] + part6[2][c][3] + part6[3][c][3] + bhh[c];
    gha[1][c] = part6[0][c][4] + part6[1][c][4] + part6[2][c][4] + part6[3][c][4] + bhh[256 + c];
    gha[2][c] = part6[0][c][5] + part6[1][c][5] + part6[2][c][5] + part6[3][c][5] + bhh[512 + c];
  }
  __syncthreads();
  // ---- gates + LN
  if (t < 256) {
    float r = 1.f / (1.f + __expf(-(gia[0][t] + gha[0][t])));
    float z = 1.f / (1.f + __expf(-(gia[1][t] + gha[1][t])));
    float nc2 = tanhf(gia[2][t] + r * gha[2][t]);
    float sn = (1.f - z) * nc2 + z * hls[t];
    sns[t] = sn;
    float a = sn, bq = sn * sn;
#pragma unroll
    for (int off = 32; off; off >>= 1) { a += __shfl_down(a, off); bq += __shfl_down(bq, off); }
    if ((t & 63) == 0) { red[t >> 6] = a; red[4 + (t >> 6)] = bq; }
  }
  __syncthreads();
  if (t < 256) {
    float S1 = red[0] + red[1] + red[2] + red[3];
    float S2 = red[4] + red[5] + red[6] + red[7];
    float mean = S1 * (1.f / 256.f);
    float var = S2 * (1.f / 256.f) - mean * mean;
    float rstd = rsqrtf(var + LN_EPS);
    lns[t] = (sns[t] - mean) * rstd * g_ml[t] + b_ml[t];
  }
  __syncthreads();
  // ---- W1
  {
    int c5 = t & 511, k5 = t >> 9;
    float acc = 0.f;
#pragma unroll 16
    for (int dd = 0; dd < 64; dd++) {
      int dp = k5 * 64 + dd;
      h16x2 wv = W1_p[dp * 512 + c5];
      acc += lns[2 * dp] * (float)wv[0] + lns[2 * dp + 1] * (float)wv[1];
    }
    part5[k5][c5] = acc;
  }
  __syncthreads();
  if (t < 512) hid[t] = fmaxf(part5[0][t] + part5[1][t] + b1[t], 0.f);
  __syncthreads();
  // ---- W2
  {
    float acc = 0.f;
#pragma unroll 16
    for (int dd = 0; dd < 64; dd++) {
      int dp = ks * 64 + dd;
      h16x2 wv = W2_p[dp * 256 + col];
      acc += hid[2 * dp] * (float)wv[0] + hid[2 * dp + 1] * (float)wv[1];
    }
    part2[ks][col] = acc;
  }
  __syncthreads();
  float outv = 0.f;
  if (t < 256) {
    outv = sns[t] + b2[t] + part2[0][t] + part2[1][t] + part2[2][t] + part2[3][t];
    slots[i * 256 + t] = outv;
  }
  // ---- fused t for next iteration
  if (cq) {
    if (t < 256) {
      float a = outv, bq = outv * outv;
#pragma unroll
      for (int off = 32; off; off >>= 1) { a += __shfl_down(a, off); bq += __shfl_down(bq, off); }
      if ((t & 63) == 0) { red[t >> 6] = a; red[4 + (t >> 6)] = bq; }
    }
    __syncthreads();
    if (t < 256) {
      float S1 = red[0] + red[1] + red[2] + red[3];
      float S2 = red[4] + red[5] + red[6] + red[7];
      float mean = S1 * (1.f / 256.f);
      float var = S2 * (1.f / 256.f) - mean * mean;
      float rstd = rsqrtf(var + LN_EPS);
      lns[t] = (outv - mean) * rstd * g_sl[t] + b_sl[t];
    }
    __syncthreads();
    // Wq
    {
      float acc = 0.f;
#pragma unroll 16
      for (int dd = 0; dd < 32; dd++) {
        int dp = ks * 32 + dd;
        h16x2 wv = Wq_p[dp * 256 + col];
        acc += lns[2 * dp] * (float)wv[0] + lns[2 * dp + 1] * (float)wv[1];
      }
      part2[ks][col] = acc;
    }
    __syncthreads();
    if (t < 256) uls[t] = part2[0][t] + part2[1][t] + part2[2][t] + part2[3][t];
    __syncthreads();
    // Wk head-projection
    int h2 = t >> 8, d2 = t & 255;
    float tt = 0.f;
#pragma unroll 8
    for (int dpp = 0; dpp < 32; dpp++) {
      h16x2 wv = WkT_p[(h2 * 32 + dpp) * 256 + d2];
      tt += uls[h2 * 64 + 2 * dpp] * (float)wv[0] + uls[h2 * 64 + 2 * dpp + 1] * (float)wv[1];
    }
    tq[(b * 32 + h2 * 8 + k) * 256 + d2] = (f16)(tt * 0.125f);
  }
}

extern "C" void kernel_launch(void* const* d_in, const int* in_sizes, int n_in,
                              void* d_out, int out_size, void* d_ws, size_t ws_size,
                              hipStream_t stream)
{
  const float* inputs = (const float*)d_in[0];
  const float* noise  = (const float*)d_in[1];
  const float* mu     = (const float*)d_in[2];
  const float* lsig   = (const float*)d_in[3];
  const float* g_in   = (const float*)d_in[4];
  const float* b_in   = (const float*)d_in[5];
  const float* g_sl   = (const float*)d_in[6];
  const float* b_sl   = (const float*)d_in[7];
  const float* g_ml   = (const float*)d_in[8];
  const float* b_ml   = (const float*)d_in[9];
  const float* Wq     = (const float*)d_in[10];
  const float* Wk     = (const float*)d_in[11];
  const float* Wv     = (const float*)d_in[12];
  const float* Wc     = (const float*)d_in[13];
  const float* wih    = (const float*)d_in[14];
  const float* whh    = (const float*)d_in[15];
  const float* bih    = (const float*)d_in[16];
  const float* bhh    = (const float*)d_in[17];
  const float* W1     = (const float*)d_in[18];
  const float* b1     = (const float*)d_in[19];
  const float* W2     = (const float*)d_in[20];
  const float* b2     = (const float*)d_in[21];

  char* ws = (char*)d_ws;
  f16*   xln16  = (f16*)(ws);                      //  67,108,864
  f16*   y_part = (f16*)(ws + 67108864);           //  16,777,216
  f16*   tq     = (f16*)(ws + 83886080);           //     524,288
  float* slots  = (float*)(ws + 84410368);         //     262,144
  float* sumsp  = (float*)(ws + 84672512);         //     131,072
  f16*   WkT16  = (f16*)(ws + 84803584);           //     131,072
  h16x2* WkT_p  = (h16x2*)(ws + 84934656);         //     131,072
  h16x2* Wv_p   = (h16x2*)(ws + 85065728);         //     131,072
  h16x2* Wc_p   = (h16x2*)(ws + 85196800);         //     131,072
  h16x2* Wq_p   = (h16x2*)(ws + 85327872);         //     131,072
  h16x2* wih_p  = (h16x2*)(ws + 85458944);         //     393,216
  h16x2* whh_p  = (h16x2*)(ws + 85852160);         //     393,216
  h16x2* W1_p   = (h16x2*)(ws + 86245376);         //     262,144
  h16x2* W2_p   = (h16x2*)(ws + 86507520);         //     262,144  -> end 86,769,664

  init_slots_k<<<256, 256, 0, stream>>>(noise, mu, lsig, slots);
  prep_w_k<<<256, 256, 0, stream>>>(Wk, Wv, Wc, wih, whh, W1, W2, Wq,
                                    WkT16, WkT_p, Wv_p, Wc_p, wih_p, whh_p,
                                    W1_p, W2_p, Wq_p);
  ln_x_k<<<2048, 256, 0, stream>>>(inputs, g_in, b_in, xln16);
  slot_t_k<<<256, 1024, 0, stream>>>(slots, g_sl, b_sl, Wq, WkT16, tq);
  for (int it = 0; it < 3; ++it) {
    attn_fused_k<<<dim3(32, 32), 256, 0, stream>>>(xln16, tq, y_part, sumsp);
    combine_k<<<256, 1024, 0, stream>>>(y_part, sumsp, slots,
                                        Wv_p, Wc_p, wih_p, whh_p, bih, bhh,
                                        g_ml, b_ml, W1_p, b1, W2_p, b2,
                                        g_sl, b_sl, Wq_p, WkT_p, tq,
                                        (it < 2) ? 1 : 0);
  }
  hipMemcpyAsync(d_out, slots, 65536 * sizeof(float), hipMemcpyDeviceToDevice, stream);
}

// Round 9
// 279.813 us; speedup vs baseline: 1.2424x; 1.2424x over previous
//
#include <hip/hip_runtime.h>
#include <hip/hip_bf16.h>
#include <stdint.h>

typedef unsigned short u16;
typedef _Float16 f16;
typedef __attribute__((ext_vector_type(4))) float f32x4;
typedef __attribute__((ext_vector_type(8))) _Float16 h16x8;
typedef __attribute__((ext_vector_type(4))) _Float16 h16x4;

#define LN_EPS 1e-5f
#define ATT_EPS 1e-8f

// ---------------- init slots: mu + exp(logsigma)*noise ----------------
__global__ __launch_bounds__(256) void init_slots_k(
    const float* __restrict__ noise, const float* __restrict__ mu,
    const float* __restrict__ lsig, float* __restrict__ slots)
{
  int i = blockIdx.x * 256 + threadIdx.x;   // 65536 total
  int d = i & 255;
  slots[i] = mu[d] + __expf(lsig[d]) * noise[i];
}

// ---------------- prep weights: WkT f16, wihT/whhT f32 ----------------
__global__ __launch_bounds__(256) void prep_w_k(
    const float* __restrict__ Wk, const float* __restrict__ wih,
    const float* __restrict__ whh,
    f16* __restrict__ WkT16, float* __restrict__ wihT, float* __restrict__ whhT)
{
  int i = blockIdx.x * 256 + threadIdx.x;   // grid 768 -> 196608
  if (i < 65536) {                           // WkT[c][kd] = Wk[kd][c]
    int c = i >> 8, kd = i & 255;
    WkT16[i] = (f16)Wk[kd * 256 + c];
  }
  int d = i / 768, j = i - d * 768;
  wihT[i] = wih[j * 256 + d];
  whhT[i] = whh[j * 256 + d];
}

// ---------------- pure LN pass: xln16 = LN(inputs) as f16 ----------------
// grid 2048, block 256 (4 waves): one wave per row, 16 rows/wave
__global__ __launch_bounds__(256) void ln_x_k(
    const float* __restrict__ inputs, const float* __restrict__ g_in,
    const float* __restrict__ b_in, f16* __restrict__ xln16)
{
  int t = threadIdx.x, w = t >> 6, l = t & 63;
  float4 gv = *(const float4*)(g_in + l * 4);
  float4 bv = *(const float4*)(b_in + l * 4);
  long row0 = (long)blockIdx.x * 64 + w * 16;
#pragma unroll 2
  for (int i = 0; i < 16; i++) {
    long r = row0 + i;
    float4 x = *(const float4*)(inputs + r * 256 + l * 4);
    float s1 = x.x + x.y + x.z + x.w;
    float s2 = x.x * x.x + x.y * x.y + x.z * x.z + x.w * x.w;
#pragma unroll
    for (int off = 1; off < 64; off <<= 1) {
      s1 += __shfl_xor(s1, off);
      s2 += __shfl_xor(s2, off);
    }
    float m = s1 * (1.f / 256.f);
    float var = s2 * (1.f / 256.f) - m * m;
    float rs = rsqrtf(var + LN_EPS);
    h16x4 o;
    o[0] = (f16)((x.x - m) * rs * gv.x + bv.x);
    o[1] = (f16)((x.y - m) * rs * gv.y + bv.y);
    o[2] = (f16)((x.z - m) * rs * gv.z + bv.z);
    o[3] = (f16)((x.w - m) * rs * gv.w + bv.w);
    *(h16x4*)(xln16 + r * 256 + l * 4) = o;
  }
}

// ---------------- t = (LN(slots)@Wq) projected through Wk heads, x SCALE ----
// grid 256 (one slot row per block), block 1024 (iter-0 only)
__global__ __launch_bounds__(1024) void slot_t_k(
    const float* __restrict__ slots, const float* __restrict__ g_sl,
    const float* __restrict__ b_sl, const float* __restrict__ Wq,
    const f16* __restrict__ WkT16, f16* __restrict__ tq)
{
  __shared__ float ln[256];
  __shared__ float qs[256];
  __shared__ float part[4][256];
  __shared__ float red[8];
  int t = threadIdx.x;
  int i = blockIdx.x;
  if (t < 256) {
    float x = slots[i * 256 + t];
    float a = x, bq = x * x;
#pragma unroll
    for (int off = 32; off; off >>= 1) { a += __shfl_down(a, off); bq += __shfl_down(bq, off); }
    if ((t & 63) == 0) { red[t >> 6] = a; red[4 + (t >> 6)] = bq; }
  }
  __syncthreads();
  if (t < 256) {
    float x = slots[i * 256 + t];
    float S1 = red[0] + red[1] + red[2] + red[3];
    float S2 = red[4] + red[5] + red[6] + red[7];
    float m = S1 * (1.f / 256.f);
    float var = S2 * (1.f / 256.f) - m * m;
    float rstd = rsqrtf(var + LN_EPS);
    ln[t] = (x - m) * rstd * g_sl[t] + b_sl[t];
  }
  __syncthreads();
  int col = t & 255, ks = t >> 8;
  float acc = 0.f;
#pragma unroll 16
  for (int dd = 0; dd < 64; dd++) {
    int d = ks * 64 + dd;
    acc += ln[d] * Wq[d * 256 + col];
  }
  part[ks][col] = acc;
  __syncthreads();
  if (t < 256) qs[t] = part[0][t] + part[1][t] + part[2][t] + part[3][t];
  __syncthreads();
  int h = t >> 8, d2 = t & 255;
  float tt = 0.f;
#pragma unroll 8
  for (int dp = 0; dp < 64; dp++)
    tt += qs[h * 64 + dp] * (float)WkT16[(h * 64 + dp) * 256 + d2];
  tq[((i >> 3) * 32 + h * 8 + (i & 7)) * 256 + d2] = (f16)(tt * 0.125f);
}

// ---------------- fused attn: MFMA dots + shuffle softmax + MFMA PV ----------
// grid (32 b, 32 nchunk of 128 n), block 256 (4 waves). 2 subtiles of 64 n.
__global__ __launch_bounds__(256, 3) void attn_fused_k(
    const f16* __restrict__ xln16, const f16* __restrict__ tq,
    f16* __restrict__ y_part, float* __restrict__ sums_part)
{
  __shared__ u16 xsT[256 * 64];      // 32KB: addr = d*128 + ((n8 ^ (d&7))<<4)
  __shared__ u16 attT[32 * 64];      // 4KB:  addr = hs*128 + ((n8 ^ (hs&7))<<4)
  __shared__ float asum_s[4][32];
  int b = blockIdx.x, nc = blockIdx.y, t = threadIdx.x;
  int nb = nc * 128;
  int w = t >> 6, l = t & 63;
  int lc = l & 15, lg = l >> 4;
  h16x8 tb0[8], tb1[8];
#pragma unroll
  for (int k0 = 0; k0 < 8; k0++) {
    tb0[k0] = *(const h16x8*)(tq + (b * 32 + lc) * 256 + k0 * 32 + lg * 8);
    tb1[k0] = *(const h16x8*)(tq + (b * 32 + lc + 16) * 256 + k0 * 32 + lg * 8);
  }
  f32x4 acc0[4], acc1[4];
#pragma unroll
  for (int dt = 0; dt < 4; dt++) { acc0[dt] = (f32x4){0,0,0,0}; acc1[dt] = (f32x4){0,0,0,0}; }
  float as0 = 0.f, as1 = 0.f;

  for (int sub = 0; sub < 2; sub++) {
    __syncthreads();
    {
      int nl8 = t >> 5, dchunk = t & 31;
      const f16* gp = xln16 + ((long)(b * 4096 + nb + sub * 64 + nl8 * 8)) * 256 + dchunk * 8;
      h16x8 v0 = *(const h16x8*)(gp);
      h16x8 v1 = *(const h16x8*)(gp + 256);
      h16x8 v2 = *(const h16x8*)(gp + 512);
      h16x8 v3 = *(const h16x8*)(gp + 768);
      h16x8 v4 = *(const h16x8*)(gp + 1024);
      h16x8 v5 = *(const h16x8*)(gp + 1280);
      h16x8 v6 = *(const h16x8*)(gp + 1536);
      h16x8 v7 = *(const h16x8*)(gp + 1792);
#pragma unroll
      for (int j = 0; j < 8; j++) {
        h16x8 o;
        o[0] = v0[j]; o[1] = v1[j]; o[2] = v2[j]; o[3] = v3[j];
        o[4] = v4[j]; o[5] = v5[j]; o[6] = v6[j]; o[7] = v7[j];
        int d = dchunk * 8 + j;
        *(h16x8*)((char*)xsT + d * 128 + ((nl8 ^ j) << 4)) = o;
      }
    }
    f32x4 D0 = {0,0,0,0}, D1 = {0,0,0,0};
    {
      const f16* ga = xln16 + ((long)(b * 4096 + nb + sub * 64 + w * 16 + lc)) * 256 + lg * 8;
#pragma unroll
      for (int k0 = 0; k0 < 8; k0++) {
        h16x8 af = *(const h16x8*)(ga + k0 * 32);
        D0 = __builtin_amdgcn_mfma_f32_16x16x32_f16(af, tb0[k0], D0, 0, 0, 0);
        D1 = __builtin_amdgcn_mfma_f32_16x16x32_f16(af, tb1[k0], D1, 0, 0, 0);
      }
    }
    h16x4 pk0, pk1;
#pragma unroll
    for (int r = 0; r < 4; r++) {
      float d0 = D0[r], d1 = D1[r];
      float m0 = d0, m1 = d1;
      m0 = fmaxf(m0, __shfl_xor(m0, 1)); m0 = fmaxf(m0, __shfl_xor(m0, 2)); m0 = fmaxf(m0, __shfl_xor(m0, 4));
      m1 = fmaxf(m1, __shfl_xor(m1, 1)); m1 = fmaxf(m1, __shfl_xor(m1, 2)); m1 = fmaxf(m1, __shfl_xor(m1, 4));
      float e0 = __expf(d0 - m0), e1 = __expf(d1 - m1);
      float s0 = e0, s1 = e1;
      s0 += __shfl_xor(s0, 1); s0 += __shfl_xor(s0, 2); s0 += __shfl_xor(s0, 4);
      s1 += __shfl_xor(s1, 1); s1 += __shfl_xor(s1, 2); s1 += __shfl_xor(s1, 4);
      f16 a0h = (f16)(e0 / s0), a1h = (f16)(e1 / s1);
      as0 += (float)a0h; as1 += (float)a1h;
      pk0[r] = a0h; pk1[r] = a1h;
    }
    {
      int slot = w * 2 + (lg >> 1);
      int boff = (lg & 1) * 8;
      *(h16x4*)((char*)attT + lc * 128 + ((slot ^ (lc & 7)) << 4) + boff) = pk0;
      *(h16x4*)((char*)attT + (lc + 16) * 128 + ((slot ^ (lc & 7)) << 4) + boff) = pk1;
    }
    __syncthreads();
    h16x8 A00, A01, A10, A11;
    {
      int hs0 = lc, hs1 = 16 + lc, sw = lc & 7;
      A00 = *(const h16x8*)((char*)attT + hs0 * 128 + ((lg ^ sw) << 4));
      A01 = *(const h16x8*)((char*)attT + hs0 * 128 + (((4 + lg) ^ sw) << 4));
      A10 = *(const h16x8*)((char*)attT + hs1 * 128 + ((lg ^ sw) << 4));
      A11 = *(const h16x8*)((char*)attT + hs1 * 128 + (((4 + lg) ^ sw) << 4));
    }
#pragma unroll
    for (int dt = 0; dt < 4; dt++) {
      int d = w * 64 + dt * 16 + lc;
      h16x8 B0 = *(const h16x8*)((char*)xsT + d * 128 + ((lg ^ (d & 7)) << 4));
      h16x8 B1 = *(const h16x8*)((char*)xsT + d * 128 + (((4 + lg) ^ (d & 7)) << 4));
      acc0[dt] = __builtin_amdgcn_mfma_f32_16x16x32_f16(A00, B0, acc0[dt], 0, 0, 0);
      acc0[dt] = __builtin_amdgcn_mfma_f32_16x16x32_f16(A01, B1, acc0[dt], 0, 0, 0);
      acc1[dt] = __builtin_amdgcn_mfma_f32_16x16x32_f16(A10, B0, acc1[dt], 0, 0, 0);
      acc1[dt] = __builtin_amdgcn_mfma_f32_16x16x32_f16(A11, B1, acc1[dt], 0, 0, 0);
    }
  }
  as0 += __shfl_xor(as0, 16); as0 += __shfl_xor(as0, 32);
  as1 += __shfl_xor(as1, 16); as1 += __shfl_xor(as1, 32);
  if (l < 16) { asum_s[w][l] = as0; asum_s[w][l + 16] = as1; }
  __syncthreads();
  if (t < 32)
    sums_part[(nc * 32 + b) * 32 + t] =
        asum_s[0][t] + asum_s[1][t] + asum_s[2][t] + asum_s[3][t];
  long ybase = ((long)(nc * 32 + b) * 32) * 256;
#pragma unroll
  for (int reg = 0; reg < 4; reg++) {
    int hsA = lg * 4 + reg;
#pragma unroll
    for (int dt = 0; dt < 4; dt++) {
      int d = w * 64 + dt * 16 + lc;
      y_part[ybase + hsA * 256 + d] = (f16)acc0[dt][reg];
      y_part[ybase + (16 + hsA) * 256 + d] = (f16)acc1[dt][reg];
    }
  }
}

// ---------------- combine: y-reduce + Wv + Wc + GRU(1-pass f32) + LN + MLP (+next-t)
// grid 256 (one slot row per block), block 1024
__global__ __launch_bounds__(1024) void combine_k(
    const f16* __restrict__ y_part, const float* __restrict__ sums_part,
    float* __restrict__ slots, const float* __restrict__ Wv,
    const float* __restrict__ Wc, const float* __restrict__ wihT,
    const float* __restrict__ whhT, const float* __restrict__ bih,
    const float* __restrict__ bhh, const float* __restrict__ g_ml,
    const float* __restrict__ b_ml, const float* __restrict__ W1,
    const float* __restrict__ b1, const float* __restrict__ W2,
    const float* __restrict__ b2, const float* __restrict__ g_sl,
    const float* __restrict__ b_sl, const float* __restrict__ Wq,
    const f16* __restrict__ WkT16, f16* __restrict__ tq, int cq)
{
  __shared__ float ysn[4][256];
  __shared__ float uls[256], cls[256], hls[256], sns[256], lns[256];
  __shared__ float hid[512];
  __shared__ float part2[4][256];
  __shared__ float part6[4][256][7];   // 6 used, 7 for bank spread
  __shared__ float part5[2][512];
  __shared__ float red[8];
  int t = threadIdx.x;
  int i = blockIdx.x;
  int b = i >> 3, k = i & 7;
  // ---- y-reduce + normalize
  {
    int j = t >> 8, d = t & 255;   // j = head
    float den = ATT_EPS, yv = 0.f;
#pragma unroll 8
    for (int ncq = 0; ncq < 32; ncq++) {
      int hsrow = (ncq * 32 + b) * 32 + j * 8 + k;
      den += sums_part[hsrow];
      yv += (float)y_part[(long)hsrow * 256 + d];
    }
    ysn[j][d] = yv / den;
    if (t < 256) hls[t] = slots[i * 256 + t];
  }
  __syncthreads();
  int col = t & 255, ks = t >> 8;
  // ---- Wv (block-diagonal per head)
  {
    int h = col >> 6;
    float acc = 0.f;
#pragma unroll 16
    for (int dd = 0; dd < 64; dd++) {
      int d = ks * 64 + dd;
      acc += ysn[h][d] * Wv[d * 256 + col];
    }
    part2[ks][col] = acc;
  }
  __syncthreads();
  if (t < 256) uls[t] = part2[0][t] + part2[1][t] + part2[2][t] + part2[3][t];
  __syncthreads();
  // ---- Wc
  {
    float acc = 0.f;
#pragma unroll 16
    for (int dd = 0; dd < 64; dd++) {
      int d = ks * 64 + dd;
      acc += uls[d] * Wc[d * 256 + col];
    }
    part2[ks][col] = acc;
  }
  __syncthreads();
  if (t < 256) cls[t] = part2[0][t] + part2[1][t] + part2[2][t] + part2[3][t];
  __syncthreads();
  // ---- GRU: all 6 gate dot-products in one pass (f32 weights)
  {
    float a0 = 0.f, a1 = 0.f, a2 = 0.f, h0 = 0.f, h1 = 0.f, h2 = 0.f;
#pragma unroll 4
    for (int dd = 0; dd < 64; dd++) {
      int d = ks * 64 + dd;
      float c = cls[d], hh = hls[d];
      const float* wi = wihT + d * 768 + col;
      const float* wh = whhT + d * 768 + col;
      a0 += c * wi[0]; a1 += c * wi[256]; a2 += c * wi[512];
      h0 += hh * wh[0]; h1 += hh * wh[256]; h2 += hh * wh[512];
    }
    part6[ks][col][0] = a0; part6[ks][col][1] = a1; part6[ks][col][2] = a2;
    part6[ks][col][3] = h0; part6[ks][col][4] = h1; part6[ks][col][5] = h2;
  }
  __syncthreads();
  // ---- gates + sn + LN-reduce (single barrier window, direct from part6)
  if (t < 256) {
    float gi0 = part6[0][t][0] + part6[1][t][0] + part6[2][t][0] + part6[3][t][0] + bih[t];
    float gi1 = part6[0][t][1] + part6[1][t][1] + part6[2][t][1] + part6[3][t][1] + bih[256 + t];
    float gi2 = part6[0][t][2] + part6[1][t][2] + part6[2][t][2] + part6[3][t][2] + bih[512 + t];
    float gh0 = part6[0][t][3] + part6[1][t][3] + part6[2][t][3] + part6[3][t][3] + bhh[t];
    float gh1 = part6[0][t][4] + part6[1][t][4] + part6[2][t][4] + part6[3][t][4] + bhh[256 + t];
    float gh2 = part6[0][t][5] + part6[1][t][5] + part6[2][t][5] + part6[3][t][5] + bhh[512 + t];
    float r = 1.f / (1.f + __expf(-(gi0 + gh0)));
    float z = 1.f / (1.f + __expf(-(gi1 + gh1)));
    float nc2 = tanhf(gi2 + r * gh2);
    float sn = (1.f - z) * nc2 + z * hls[t];
    sns[t] = sn;
    float a = sn, bq = sn * sn;
#pragma unroll
    for (int off = 32; off; off >>= 1) { a += __shfl_down(a, off); bq += __shfl_down(bq, off); }
    if ((t & 63) == 0) { red[t >> 6] = a; red[4 + (t >> 6)] = bq; }
  }
  __syncthreads();
  if (t < 256) {
    float S1 = red[0] + red[1] + red[2] + red[3];
    float S2 = red[4] + red[5] + red[6] + red[7];
    float mean = S1 * (1.f / 256.f);
    float var = S2 * (1.f / 256.f) - mean * mean;
    float rstd = rsqrtf(var + LN_EPS);
    lns[t] = (sns[t] - mean) * rstd * g_ml[t] + b_ml[t];
  }
  __syncthreads();
  // ---- W1
  {
    int c5 = t & 511, k5 = t >> 9;
    float acc = 0.f;
#pragma unroll 16
    for (int dd = 0; dd < 128; dd++) {
      int d = k5 * 128 + dd;
      acc += lns[d] * W1[d * 512 + c5];
    }
    part5[k5][c5] = acc;
  }
  __syncthreads();
  if (t < 512) hid[t] = fmaxf(part5[0][t] + part5[1][t] + b1[t], 0.f);
  __syncthreads();
  // ---- W2
  {
    float acc = 0.f;
#pragma unroll 16
    for (int dd = 0; dd < 128; dd++) {
      int d = ks * 128 + dd;
      acc += hid[d] * W2[d * 256 + col];
    }
    part2[ks][col] = acc;
  }
  __syncthreads();
  float outv = 0.f;
  if (t < 256) {
    outv = sns[t] + b2[t] + part2[0][t] + part2[1][t] + part2[2][t] + part2[3][t];
    slots[i * 256 + t] = outv;
  }
  // ---- fused t for next iteration
  if (cq) {
    if (t < 256) {
      float a = outv, bq = outv * outv;
#pragma unroll
      for (int off = 32; off; off >>= 1) { a += __shfl_down(a, off); bq += __shfl_down(bq, off); }
      if ((t & 63) == 0) { red[t >> 6] = a; red[4 + (t >> 6)] = bq; }
    }
    __syncthreads();
    if (t < 256) {
      float S1 = red[0] + red[1] + red[2] + red[3];
      float S2 = red[4] + red[5] + red[6] + red[7];
      float mean = S1 * (1.f / 256.f);
      float var = S2 * (1.f / 256.f) - mean * mean;
      float rstd = rsqrtf(var + LN_EPS);
      lns[t] = (outv - mean) * rstd * g_sl[t] + b_sl[t];
    }
    __syncthreads();
    float accq = 0.f;
#pragma unroll 16
    for (int dd = 0; dd < 64; dd++) {
      int d = ks * 64 + dd;
      accq += lns[d] * Wq[d * 256 + col];
    }
    part2[ks][col] = accq;
    __syncthreads();
    if (t < 256) uls[t] = part2[0][t] + part2[1][t] + part2[2][t] + part2[3][t];
    __syncthreads();
    int h2 = t >> 8, d2 = t & 255;
    float tt = 0.f;
#pragma unroll 8
    for (int dp = 0; dp < 64; dp++)
      tt += uls[h2 * 64 + dp] * (float)WkT16[(h2 * 64 + dp) * 256 + d2];
    tq[(b * 32 + h2 * 8 + k) * 256 + d2] = (f16)(tt * 0.125f);
  }
}

extern "C" void kernel_launch(void* const* d_in, const int* in_sizes, int n_in,
                              void* d_out, int out_size, void* d_ws, size_t ws_size,
                              hipStream_t stream)
{
  const float* inputs = (const float*)d_in[0];
  const float* noise  = (const float*)d_in[1];
  const float* mu     = (const float*)d_in[2];
  const float* lsig   = (const float*)d_in[3];
  const float* g_in   = (const float*)d_in[4];
  const float* b_in   = (const float*)d_in[5];
  const float* g_sl   = (const float*)d_in[6];
  const float* b_sl   = (const float*)d_in[7];
  const float* g_ml   = (const float*)d_in[8];
  const float* b_ml   = (const float*)d_in[9];
  const float* Wq     = (const float*)d_in[10];
  const float* Wk     = (const float*)d_in[11];
  const float* Wv     = (const float*)d_in[12];
  const float* Wc     = (const float*)d_in[13];
  const float* wih    = (const float*)d_in[14];
  const float* whh    = (const float*)d_in[15];
  const float* bih    = (const float*)d_in[16];
  const float* bhh    = (const float*)d_in[17];
  const float* W1     = (const float*)d_in[18];
  const float* b1     = (const float*)d_in[19];
  const float* W2     = (const float*)d_in[20];
  const float* b2     = (const float*)d_in[21];

  char* ws = (char*)d_ws;
  f16*   xln16  = (f16*)(ws);                      //  67,108,864
  f16*   y_part = (f16*)(ws + 67108864);           //  16,777,216
  f16*   tq     = (f16*)(ws + 83886080);           //     524,288
  float* slots  = (float*)(ws + 84410368);         //     262,144
  float* sumsp  = (float*)(ws + 84672512);         //     131,072
  f16*   WkT16  = (f16*)(ws + 84803584);           //     131,072
  float* wihT   = (float*)(ws + 84934656);         //     786,432
  float* whhT   = (float*)(ws + 85721088);         //     786,432  -> end 86,507,520

  init_slots_k<<<256, 256, 0, stream>>>(noise, mu, lsig, slots);
  prep_w_k<<<768, 256, 0, stream>>>(Wk, wih, whh, WkT16, wihT, whhT);
  ln_x_k<<<2048, 256, 0, stream>>>(inputs, g_in, b_in, xln16);
  slot_t_k<<<256, 1024, 0, stream>>>(slots, g_sl, b_sl, Wq, WkT16, tq);
  for (int it = 0; it < 3; ++it) {
    attn_fused_k<<<dim3(32, 32), 256, 0, stream>>>(xln16, tq, y_part, sumsp);
    combine_k<<<256, 1024, 0, stream>>>(y_part, sumsp, slots, Wv, Wc, wihT, whhT,
                                        bih, bhh, g_ml, b_ml, W1, b1, W2, b2,
                                        g_sl, b_sl, Wq, WkT16, tq, (it < 2) ? 1 : 0);
  }
  hipMemcpyAsync(d_out, slots, 65536 * sizeof(float), hipMemcpyDeviceToDevice, stream);
}